// Round 11
// baseline (418.105 us; speedup 1.0000x reference)
//
#include <hip/hip_runtime.h>
#include <cstdint>
#include <cstddef>

typedef unsigned short u16;
using f16x8 = __attribute__((ext_vector_type(8))) _Float16;
using f32x4 = __attribute__((ext_vector_type(4))) float;
using u16x4 = __attribute__((ext_vector_type(4))) unsigned short;

// float -> fp16 bit pattern (round-to-nearest-even via v_cvt_f16_f32)
__device__ __forceinline__ u16 f2h(float f) {
  union { _Float16 h; u16 u; } c;
  c.h = (_Float16)f;
  return c.u;
}

// async global->LDS, 16B per lane. LDS dest must be wave-uniform base; HW writes base + lane*16.
__device__ __forceinline__ void gl_lds16(const void* g, void* lds) {
  __builtin_amdgcn_global_load_lds(
      (const __attribute__((address_space(1))) void*)(uintptr_t)g,
      (__attribute__((address_space(3))) void*)(uint32_t)(uintptr_t)lds,
      16, 0, 0);
}

// counted vmcnt wait (inline asm, literal immediate)
template <int N> __device__ __forceinline__ void vmcnt_wait() {
  if constexpr (N == 0)      asm volatile("s_waitcnt vmcnt(0)" ::: "memory");
  else if constexpr (N == 3) asm volatile("s_waitcnt vmcnt(3)" ::: "memory");
  else if constexpr (N == 4) asm volatile("s_waitcnt vmcnt(4)" ::: "memory");
  else static_assert(N == 0, "unsupported vmcnt literal");
}

// raw workgroup barrier (no vmcnt(0) drain)
__device__ __forceinline__ void block_sync() {
  asm volatile("" ::: "memory");
  __builtin_amdgcn_s_barrier();
  asm volatile("" ::: "memory");
}

// ---------------------------------------------------------------------------
// Stage a ROWS x 32 u16 K-tile with SOURCE-side XOR swizzle (rule #21).
// ---------------------------------------------------------------------------
template <int ROWS>
__device__ __forceinline__ void stage32(const u16* g, int ldk, u16* lds, int t) {
#pragma unroll
  for (int i = 0; i < ROWS / 128; ++i) {
    const int s   = i * 512 + t;
    const int row = s >> 2;
    const int gc  = (s & 3) ^ ((s >> 3) & 3);
    gl_lds16(g + (size_t)row * ldk + gc * 8,
             lds + (size_t)(i * 512 + (t & ~63)) * 8);
  }
}

template <int NF>
__device__ __forceinline__ void compute_tile32(
    const u16* pA, const u16* pB, f32x4 (&acc)[8][NF],
    int wm, int wn, int lm, int cq)
{
  f16x8 bf[NF];
#pragma unroll
  for (int nf = 0; nf < NF; ++nf)
    bf[nf] = *(const f16x8*)(pB + (wn + nf * 16 + lm) * 32 + cq * 8);
  __builtin_amdgcn_s_setprio(1);   // T5: favor this wave while MFMA cluster runs
#pragma unroll
  for (int mf = 0; mf < 8; ++mf) {
    f16x8 a0 = *(const f16x8*)(pA + (wm + mf * 16 + lm) * 32 + cq * 8);
#pragma unroll
    for (int nf = 0; nf < NF; ++nf)
      acc[mf][nf] = __builtin_amdgcn_mfma_f32_16x16x32_f16(a0, bf[nf], acc[mf][nf], 0, 0, 0);
  }
  __builtin_amdgcn_s_setprio(0);
}

// ---------------------------------------------------------------------------
// bt-GEMM, 256 x BN tile, BK=32, 4-buffer counted-vmcnt pipeline (round-3
// validated). Requires M%256==0, Ncols%BN==0, K%128==0.
// MODE 0: fp16 out (+bias). MODE 1: fp32 out (NON-TEMPORAL: bypass L2 so the
// reused A/B panels stay resident — S is only re-read via L3 anyway).
// MODE 2: fp32 elu out (non-temporal, same reasoning).
// SWZ 1: XCD-aware remap (requires gridDim.z==8): lin%8 -> batch, so each
// XCD (round-robin over linear dispatch id) owns exactly one batch's blocks.
// ---------------------------------------------------------------------------
template <int BN, int MODE, int SWZ>
__global__ __launch_bounds__(512, 2) void gemm32(
    const u16* __restrict__ A, const u16* __restrict__ Bt,
    void* __restrict__ Cv, const float* __restrict__ bias,
    int M, int Ncols, int K,
    long long strideA, long long strideB, long long strideC)
{
  constexpr int NF  = BN / 64;
  constexpr int LPT = 2 + BN / 128;

  __shared__ __align__(16) u16 sA0[256 * 32];
  __shared__ __align__(16) u16 sA1[256 * 32];
  __shared__ __align__(16) u16 sA2[256 * 32];
  __shared__ __align__(16) u16 sA3[256 * 32];
  __shared__ __align__(16) u16 sB0[BN * 32];
  __shared__ __align__(16) u16 sB1[BN * 32];
  __shared__ __align__(16) u16 sB2[BN * 32];
  __shared__ __align__(16) u16 sB3[BN * 32];

  int bx = blockIdx.x, by = blockIdx.y, bz = blockIdx.z;
  if (SWZ) {
    const int lin = blockIdx.x + gridDim.x * (blockIdx.y + gridDim.y * blockIdx.z);
    const int c = lin & 7;      // XCD under round-robin dispatch
    const int i = lin >> 3;     // per-XCD block index
    bz = c;
    bx = i % gridDim.x;
    by = i / gridDim.x;
  }

  A  += (size_t)bz * strideA;
  Bt += (size_t)bz * strideB;

  const int m0 = by * 256;
  const int n0 = bx * BN;
  const int t    = threadIdx.x;
  const int lane = t & 63;
  const int wave = t >> 6;
  const int wm   = (wave >> 2) * 128;
  const int wn   = (wave & 3) * (BN / 4);
  const int lm   = lane & 15;
  const int quad = lane >> 4;
  const int cq   = quad ^ ((lm >> 1) & 3);

  f32x4 acc[8][NF];
#pragma unroll
  for (int i = 0; i < 8; ++i)
#pragma unroll
    for (int j = 0; j < NF; ++j) acc[i][j] = f32x4{0.f, 0.f, 0.f, 0.f};

  const u16* Ag = A + (size_t)m0 * K;
  const u16* Bg = Bt + (size_t)n0 * K;

  const int nk = K >> 5;

  stage32<256>(Ag,      K, sA0, t);  stage32<BN>(Bg,      K, sB0, t);
  stage32<256>(Ag + 32, K, sA1, t);  stage32<BN>(Bg + 32, K, sB1, t);

  for (int kt = 0; kt < nk - 4; kt += 4) {
    vmcnt_wait<LPT>(); block_sync();
    stage32<256>(Ag + (size_t)(kt + 2) * 32, K, sA2, t);
    stage32<BN >(Bg + (size_t)(kt + 2) * 32, K, sB2, t);
    compute_tile32<NF>(sA0, sB0, acc, wm, wn, lm, cq);

    vmcnt_wait<LPT>(); block_sync();
    stage32<256>(Ag + (size_t)(kt + 3) * 32, K, sA3, t);
    stage32<BN >(Bg + (size_t)(kt + 3) * 32, K, sB3, t);
    compute_tile32<NF>(sA1, sB1, acc, wm, wn, lm, cq);

    vmcnt_wait<LPT>(); block_sync();
    stage32<256>(Ag + (size_t)(kt + 4) * 32, K, sA0, t);
    stage32<BN >(Bg + (size_t)(kt + 4) * 32, K, sB0, t);
    compute_tile32<NF>(sA2, sB2, acc, wm, wn, lm, cq);

    vmcnt_wait<LPT>(); block_sync();
    stage32<256>(Ag + (size_t)(kt + 5) * 32, K, sA1, t);
    stage32<BN >(Bg + (size_t)(kt + 5) * 32, K, sB1, t);
    compute_tile32<NF>(sA3, sB3, acc, wm, wn, lm, cq);
  }

  vmcnt_wait<LPT>(); block_sync();
  stage32<256>(Ag + (size_t)(nk - 2) * 32, K, sA2, t);
  stage32<BN >(Bg + (size_t)(nk - 2) * 32, K, sB2, t);
  compute_tile32<NF>(sA0, sB0, acc, wm, wn, lm, cq);

  vmcnt_wait<LPT>(); block_sync();
  stage32<256>(Ag + (size_t)(nk - 1) * 32, K, sA3, t);
  stage32<BN >(Bg + (size_t)(nk - 1) * 32, K, sB3, t);
  compute_tile32<NF>(sA1, sB1, acc, wm, wn, lm, cq);

  vmcnt_wait<LPT>(); block_sync();
  compute_tile32<NF>(sA2, sB2, acc, wm, wn, lm, cq);

  vmcnt_wait<0>(); block_sync();
  compute_tile32<NF>(sA3, sB3, acc, wm, wn, lm, cq);

  if (MODE == 0) {
    u16* C = (u16*)Cv + (size_t)bz * strideC;
#pragma unroll
    for (int nf = 0; nf < NF; ++nf) {
      const int col = n0 + wn + nf * 16 + lm;
      const float bv = bias ? bias[col] : 0.f;
#pragma unroll
      for (int mf = 0; mf < 8; ++mf)
#pragma unroll
        for (int r = 0; r < 4; ++r) {
          const int row = m0 + wm + mf * 16 + quad * 4 + r;
          C[(size_t)row * Ncols + col] = f2h(acc[mf][nf][r] + bv);
        }
    }
  } else {
    float* C = (float*)Cv + (size_t)bz * strideC;
#pragma unroll
    for (int nf = 0; nf < NF; ++nf) {
      const int col = n0 + wn + nf * 16 + lm;
#pragma unroll
      for (int mf = 0; mf < 8; ++mf)
#pragma unroll
        for (int r = 0; r < 4; ++r) {
          const int row = m0 + wm + mf * 16 + quad * 4 + r;
          float v = acc[mf][nf][r];
          if (MODE == 2) v = v > 0.f ? v : expm1f(v);
          // streaming output: non-temporal, keep A/B panels resident in L2
          __builtin_nontemporal_store(v, &C[(size_t)row * Ncols + col]);
        }
    }
  }
}

// ---------------------------------------------------------------------------
// masked softmax over one row of 2048: P = softmax(where(adj==0, -inf, S)), fp16 out
// ---------------------------------------------------------------------------
__global__ __launch_bounds__(256) void masked_softmax(
    const float* __restrict__ S, const int* __restrict__ adj, u16* __restrict__ P)
{
  const size_t row = blockIdx.x;
  const float* s = S + row * 2048;
  const int*   a = adj + row * 2048;
  u16*         p = P + row * 2048;
  const int t = threadIdx.x;

  float v[8];
#pragma unroll
  for (int i = 0; i < 2; ++i) {
    float4 sv = ((const float4*)s)[t + i * 256];
    int4   av = ((const int4*)a)[t + i * 256];
    v[i * 4 + 0] = av.x ? sv.x : -1e30f;
    v[i * 4 + 1] = av.y ? sv.y : -1e30f;
    v[i * 4 + 2] = av.z ? sv.z : -1e30f;
    v[i * 4 + 3] = av.w ? sv.w : -1e30f;
  }
  float mx = v[0];
#pragma unroll
  for (int i = 1; i < 8; ++i) mx = fmaxf(mx, v[i]);
#pragma unroll
  for (int o = 32; o > 0; o >>= 1) mx = fmaxf(mx, __shfl_xor(mx, o));
  __shared__ float red[4];
  if ((t & 63) == 0) red[t >> 6] = mx;
  __syncthreads();
  mx = fmaxf(fmaxf(red[0], red[1]), fmaxf(red[2], red[3]));
  __syncthreads();

  float e[8]; float sum = 0.f;
#pragma unroll
  for (int i = 0; i < 8; ++i) { e[i] = __expf(v[i] - mx); sum += e[i]; }
#pragma unroll
  for (int o = 32; o > 0; o >>= 1) sum += __shfl_xor(sum, o);
  if ((t & 63) == 0) red[t >> 6] = sum;
  __syncthreads();
  sum = red[0] + red[1] + red[2] + red[3];
  const float inv = 1.f / sum;

#pragma unroll
  for (int i = 0; i < 2; ++i) {
    u16x4 o4;
    o4[0] = f2h(e[i * 4 + 0] * inv);
    o4[1] = f2h(e[i * 4 + 1] * inv);
    o4[2] = f2h(e[i * 4 + 2] * inv);
    o4[3] = f2h(e[i * 4 + 3] * inv);
    ((u16x4*)p)[t + i * 256] = o4;
  }
}

// ---------------------------------------------------------------------------
// 16-bit transpose per batch (z): in [R][C] -> out [C][R], 64x64 LDS tiles
// ---------------------------------------------------------------------------
__global__ __launch_bounds__(256) void transpose_u16(
    const u16* __restrict__ in, u16* __restrict__ outp, int R, int C)
{
  __shared__ u16 tile[64][65];
  const size_t base = (size_t)blockIdx.z * R * C;
  const int r0 = blockIdx.y * 64, c0 = blockIdx.x * 64;
  const int t = threadIdx.x;
  const int c = t & 63, rr = t >> 6;
#pragma unroll
  for (int i = 0; i < 16; ++i) {
    const int r = rr + i * 4;
    tile[r][c] = in[base + (size_t)(r0 + r) * C + c0 + c];
  }
  __syncthreads();
  const int rp = t & 63, cc = t >> 6;
#pragma unroll
  for (int i = 0; i < 16; ++i) {
    const int cq2 = cc + i * 4;
    outp[base + (size_t)(c0 + cq2) * R + r0 + rp] = tile[rp][cq2];
  }
}

__global__ __launch_bounds__(256) void cvt_f32_f16(
    const float* __restrict__ in, u16* __restrict__ outp, int n4)
{
  const int i = blockIdx.x * 256 + threadIdx.x;
  if (i >= n4) return;
  float4 v = ((const float4*)in)[i];
  u16x4 o; o[0] = f2h(v.x); o[1] = f2h(v.y); o[2] = f2h(v.z); o[3] = f2h(v.w);
  ((u16x4*)outp)[i] = o;
}

// out[j*R + i] = fp16(in[i*C + j])  (coalesced reads, tiny matrix)
__global__ __launch_bounds__(256) void transpose_cvt(
    const float* __restrict__ in, u16* __restrict__ outp, int R, int C)
{
  const int idx = blockIdx.x * 256 + threadIdx.x;
  const int i = idx / C, j = idx % C;
  outp[(size_t)j * R + i] = f2h(in[idx]);
}

// ---------------------------------------------------------------------------
extern "C" void kernel_launch(void* const* d_in, const int* in_sizes, int n_in,
                              void* d_out, int out_size, void* d_ws, size_t ws_size,
                              hipStream_t stream) {
  (void)in_sizes; (void)n_in; (void)out_size;
  const float* x    = (const float*)d_in[0];
  const int*   adj  = (const int*)d_in[1];
  const float* W    = (const float*)d_in[2];
  const float* bvec = (const float*)d_in[3];
  const float* attn = (const float*)d_in[4];
  float* out = (float*)d_out;

  constexpr int B = 8, N = 2048, D = 512;
  constexpr size_t MN = (size_t)B * N;  // 16384

  char* ws = (char*)d_ws;
  size_t off = 0;
  auto take = [&](size_t bytes) -> char* {
    char* p = ws + off;
    off += (bytes + 255) & ~(size_t)255;
    return p;
  };
  u16* xh   = (u16*)take(MN * D * 2);
  u16* Wh   = (u16*)take((size_t)D * D * 2);
  u16* attT = (u16*)take((size_t)D * D * 2);
  u16* h    = (u16*)take(MN * D * 2);
  u16* hT   = (u16*)take(MN * D * 2);
  u16* ha   = (u16*)take(MN * D * 2);

  auto al = [](size_t b) { return (b + 255) & ~(size_t)255; };
  const size_t szSf = al((size_t)B * N * N * 4), szPf = al((size_t)B * N * N * 2);
  const size_t szSb = al((size_t)N * N * 4),     szPb = al((size_t)N * N * 2);
  const bool full  = ws_size >= off + szSf + szPf;
  const bool ok_pb = ws_size >= off + szSb + szPb;
  if (!full && !ok_pb) return;  // ws too small; fail validation cleanly

  // converts
  cvt_f32_f16<<<dim3((unsigned)(MN * D / 4 / 256)), 256, 0, stream>>>(x, xh, (int)(MN * D / 4));
  cvt_f32_f16<<<dim3(D * D / 4 / 256), 256, 0, stream>>>(W, Wh, D * D / 4);
  transpose_cvt<<<dim3(D * D / 256), 256, 0, stream>>>(attn, attT, D, D);

  // K1: h = xh . Wh^T + bias   [16384,512] x [512,512]
  gemm32<128, 0, 0><<<dim3(D / 128, MN / 256, 1), 512, 0, stream>>>(
      xh, Wh, h, bvec, (int)MN, D, D, 0, 0, 0);
  // hT per batch: [2048,512] -> [512,2048]
  transpose_u16<<<dim3(D / 64, N / 64, B), 256, 0, stream>>>(h, hT, N, D);
  // K2: ha = h . attT^T
  gemm32<128, 0, 0><<<dim3(D / 128, MN / 256, 1), 512, 0, stream>>>(
      h, attT, ha, nullptr, (int)MN, D, D, 0, 0, 0);

  if (full) {
    float* S = (float*)take(szSf);
    u16*   P = (u16*)take(szPf);
    // K3: S = ha . h^T per batch  (256x256 tiles; XCD-swizzled; nt S-stores)
    gemm32<256, 1, 1><<<dim3(N / 256, N / 256, B), 512, 0, stream>>>(
        ha, h, S, nullptr, N, N, D,
        (long long)N * D, (long long)N * D, (long long)N * N);
    // K4: masked softmax -> P fp16
    masked_softmax<<<dim3((unsigned)(B * N)), 256, 0, stream>>>(S, adj, P);
    // K5: out = elu(P . hT^T) per batch  (XCD-swizzled; nt out-stores)
    gemm32<128, 2, 1><<<dim3(D / 128, N / 256, B), 512, 0, stream>>>(
        P, hT, out, nullptr, N, D, N,
        (long long)N * N, (long long)D * N, (long long)N * D);
  } else {
    float* S = (float*)take(szSb);
    u16*   P = (u16*)take(szPb);
    for (int b = 0; b < B; ++b) {
      gemm32<256, 1, 0><<<dim3(N / 256, N / 256, 1), 512, 0, stream>>>(
          ha + (size_t)b * N * D, h + (size_t)b * N * D, S, nullptr, N, N, D, 0, 0, 0);
      masked_softmax<<<dim3(N), 256, 0, stream>>>(S, adj + (size_t)b * N * N, P);
      gemm32<128, 2, 0><<<dim3(D / 128, N / 256, 1), 512, 0, stream>>>(
          P, hT + (size_t)b * D * N, out + (size_t)b * N * D, nullptr, N, D, N, 0, 0, 0);
    }
  }
}